// Round 5
// baseline (16030.280 us; speedup 1.0000x reference)
//
#include <hip/hip_runtime.h>
#include <stdint.h>

#define TT 2048
#define BB 32
#define II 512
#define HH 512
#define BHE (BB * HH)      // 16384 elements per [B,H] slab
#define NWGL 32            // workgroups per layer
#define NT 512             // 8 waves per WG
#define RING 16            // y0 ring slots (L0 state + L0->L1 pipe)

typedef unsigned short u16;
typedef unsigned int u32;
typedef __attribute__((ext_vector_type(8))) short bf16x8;
typedef __attribute__((ext_vector_type(4))) float f32x4;

__device__ __forceinline__ u16 f2bf(float f) {
  u32 u = __float_as_uint(f);
  return (u16)((u + 0x7fffu + ((u >> 16) & 1u)) >> 16);  // RNE
}
__device__ __forceinline__ float bf2f(u16 h) { return __uint_as_float(((u32)h) << 16); }
__device__ __forceinline__ float sigm(float x) { return 1.f / (1.f + __expf(-x)); }
__device__ __forceinline__ float tanh_(float x) {
  float xc = fminf(fmaxf(x, -15.f), 15.f);
  float e = __expf(-2.f * xc);
  return (1.f - e) / (1.f + e);
}

// L1/L2-bypassing comm accesses (coherence point = MALL; proven R2/R3)
__device__ __forceinline__ bf16x8 ld128_sys(const u16* p) {
  bf16x8 r; asm volatile("global_load_dwordx4 %0, %1, off sc0 sc1" : "=v"(r) : "v"(p) : "memory"); return r;
}
__device__ __forceinline__ void st16_sys(u16* p, u16 v) {
  u32 vv = v; asm volatile("global_store_short %0, %1, off sc0 sc1" :: "v"(p), "v"(vv) : "memory");
}

#define SCHED0() __builtin_amdgcn_sched_barrier(0)

// ---- prep: x fp32 -> 2-limb bf16 ----
__global__ void k_cvt_x(const float* __restrict__ x, u16* __restrict__ xh, u16* __restrict__ xl) {
  const long n = (long)TT * BB * II;
  long i = ((long)blockIdx.x * 256 + threadIdx.x) * 4;
  const long stride = (long)gridDim.x * 256 * 4;
  for (; i < n; i += stride) {
    float4 v = *(const float4*)(x + i);
    ushort4 h, l;
    h.x = f2bf(v.x); l.x = f2bf(v.x - bf2f(h.x));
    h.y = f2bf(v.y); l.y = f2bf(v.y - bf2f(h.y));
    h.z = f2bf(v.z); l.z = f2bf(v.z - bf2f(h.z));
    h.w = f2bf(v.w); l.w = f2bf(v.w - bf2f(h.w));
    *(ushort4*)(xh + i) = h;
    *(ushort4*)(xl + i) = l;
  }
}

// ---- prep: gate-permuted 2-limb weights. rr = hidx*4+q, srow = q*512+hidx ----
__global__ void k_build_w(const float* __restrict__ Wih0, const float* __restrict__ Whh0,
                          const float* __restrict__ bih0, const float* __restrict__ bhh0,
                          const float* __restrict__ Wih1, const float* __restrict__ Whh1,
                          const float* __restrict__ bih1, const float* __restrict__ bhh1,
                          u16* __restrict__ WH0, u16* __restrict__ WL0,
                          u16* __restrict__ WH1, u16* __restrict__ WL1,
                          float* __restrict__ bsum0, float* __restrict__ bsum1) {
  const int rr = blockIdx.x & 2047;
  const int layer = blockIdx.x >> 11;
  const float* Wih = layer ? Wih1 : Wih0;
  const float* Whh = layer ? Whh1 : Whh0;
  u16* WH = (layer ? WH1 : WH0) + ((size_t)rr << 10);
  u16* WL = (layer ? WL1 : WL0) + ((size_t)rr << 10);
  const int hidx = rr >> 2, q = rr & 3;
  const int srow = q * HH + hidx;
  const float* si = Wih + (size_t)srow * II;
  const float* sh = Whh + (size_t)srow * HH;
  for (int k = threadIdx.x; k < 512; k += 256) {
    float wi = si[k]; u16 a = f2bf(wi); WH[k] = a;       WL[k] = f2bf(wi - bf2f(a));
    float wh = sh[k]; u16 b = f2bf(wh); WH[512 + k] = b; WL[512 + k] = f2bf(wh - bf2f(b));
  }
  if (threadIdx.x == 0)
    (layer ? bsum1 : bsum0)[rr] = (layer ? bih1 : bih0)[srow] + (layer ? bhh1 : bhh0)[srow];
}

// ---- prep: h0 -> 2-limb state (y0 ring slot 0 / h1 slot 0), zero flags ----
__global__ void k_init(const float* __restrict__ h0,
                       u16* __restrict__ y0h, u16* __restrict__ y0l,
                       u16* __restrict__ h1h, u16* __restrict__ h1l,
                       u32* __restrict__ slots) {
  int i = blockIdx.x * 256 + threadIdx.x;
  if (i < BHE) {
    float v = h0[i]; u16 h = f2bf(v);
    y0h[i] = h; y0l[i] = f2bf(v - bf2f(h));
  } else if (i < 2 * BHE) {
    int j = i - BHE; float v = h0[i]; u16 h = f2bf(v);
    h1h[j] = h; h1l[j] = f2bf(v - bf2f(h));
  }
  if (i < 64) slots[i] = 0;   // [2][32] completed-step flags
}

// ---- persistent scan: blocks 0..31 = layer0, 32..63 = layer1 (pipelined) ----
// WG: 64 gate rows (16 h) x full batch 32. 8 waves = 8 K-slices(128).
// Each wave: 4 row-tiles x 2 col-tiles x (K=128) -> 96 MFMAs (3 limb-products).
// Weights (2-limb) register-resident: 32 frags = 128 VGPR per wave.
__global__ __launch_bounds__(NT, 2) void k_scan(
    const u16* __restrict__ WH0, const u16* __restrict__ WL0,
    const u16* __restrict__ WH1, const u16* __restrict__ WL1,
    const float* __restrict__ bsum0, const float* __restrict__ bsum1,
    const u16* __restrict__ xh, const u16* __restrict__ xl,
    u16* __restrict__ y0h, u16* __restrict__ y0l,   // [RING][B][H] 2-limb
    u16* __restrict__ h1h, u16* __restrict__ h1l,   // [2][B][H] 2-limb
    const float* __restrict__ c0, float* __restrict__ out,
    u32* __restrict__ slots) {
  __shared__ f32x4 red[8][8][64];   // 64 KiB: [wave][tile][lane] partial sums

  const int layer = blockIdx.x >> 5;
  const int wg = blockIdx.x & 31;
  const int tid = threadIdx.x;
  const int ln = tid & 63;
  const int wv = tid >> 6;          // wave id = K-slice kq = finalize tile
  const int kq = wv;
  const int l15 = ln & 15, l16 = ln >> 4;
  const int koff = l16 * 8;

  const u16* WHp = layer ? WH1 : WH0;
  const u16* WLp = layer ? WL1 : WL0;

  // ---- stage this wave's A-fragments into registers, once ----
  bf16x8 wh[4][4], wl[4][4];
#pragma unroll
  for (int rt = 0; rt < 4; ++rt) {
    const size_t row = (size_t)(wg * 64 + rt * 16 + l15) << 10;
#pragma unroll
    for (int kk = 0; kk < 4; ++kk) {
      const size_t kpos = (size_t)kq * 128 + kk * 32 + koff;
      wh[rt][kk] = *(const bf16x8*)(WHp + row + kpos);
      wl[rt][kk] = *(const bf16x8*)(WLp + row + kpos);
    }
  }
#pragma unroll
  for (int rt = 0; rt < 4; ++rt)
#pragma unroll
    for (int kk = 0; kk < 4; ++kk)
      asm volatile("" : "+v"(wh[rt][kk]), "+v"(wl[rt][kk]));

  // finalize identity: wave wv owns tile (rt_f, ct_f)
  const int rt_f = wv >> 1, ct_f = wv & 1;
  const int hidx = wg * 16 + rt_f * 4 + l16;
  const int bcol = ct_f * 16 + l15;
  const float* bsum = layer ? bsum1 : bsum0;
  f32x4 bias = *(const f32x4*)(bsum + hidx * 4);
  float creg = c0[layer * BHE + bcol * HH + hidx];

  u32* ownS = slots + layer * 32;
  u32* othS = slots + (1 - layer) * 32;
  float* hnp = out + (size_t)TT * BHE + (size_t)layer * BHE;
  float* cnp = out + (size_t)TT * BHE + 2 * BHE + (size_t)layer * BHE;

  const bool xwave = (layer == 0) && (kq < 4);

  for (int t = 0; t < TT; ++t) {
    bf16x8 pbh[2][4], pbl[2][4];

    // phase A: flag-independent x prefetch (normal cached loads; read-only data)
    if (xwave) {
      const size_t xo = (size_t)t * BHE + (size_t)kq * 128;
#pragma unroll
      for (int ct = 0; ct < 2; ++ct) {
        const size_t cb = (size_t)(ct * 16 + l15) * 512 + koff;
#pragma unroll
        for (int kk = 0; kk < 4; ++kk) {
          pbh[ct][kk] = *(const bf16x8*)(xh + xo + cb + kk * 32);
          pbl[ct][kk] = *(const bf16x8*)(xl + xo + cb + kk * 32);
        }
      }
    }

    // phase B: wave 0 polls flags. lanes 0-31: own layer >= t.
    // lanes 32-63: L1 watches L0 >= t+1; L0 watches L1 >= t-15 (ring backpressure, t>=16).
    if (wv == 0) {
      const u32 tgtOwn = (u32)t;
      int needO; u32 tgtO;
      if (layer == 0) { needO = (t >= 16); tgtO = (u32)(t - 15); }
      else            { needO = 1;         tgtO = (u32)(t + 1); }
      for (;;) {
        int ok = 1;
        if (ln < 32) ok = (__hip_atomic_load(&ownS[ln], __ATOMIC_RELAXED, __HIP_MEMORY_SCOPE_AGENT) >= tgtOwn);
        else if (needO) ok = (__hip_atomic_load(&othS[ln - 32], __ATOMIC_RELAXED, __HIP_MEMORY_SCOPE_AGENT) >= tgtO);
        if (__all(ok)) break;
        __builtin_amdgcn_s_sleep(1);
      }
    }
    __syncthreads();   // barrier 1: flags satisfied -> state readable

    // phase C: communicated-state B loads (MALL bypass)
    if (!xwave) {
      const u16 *bh_base, *bl_base;
      if (layer == 0) {                      // kq 4-7: L0 h-part = y0 ring slot t
        const size_t so = (size_t)(t & (RING - 1)) * BHE + (size_t)(kq - 4) * 128;
        bh_base = y0h + so; bl_base = y0l + so;
      } else if (kq < 4) {                   // L1 x-part = y0 ring slot t+1
        const size_t so = (size_t)((t + 1) & (RING - 1)) * BHE + (size_t)kq * 128;
        bh_base = y0h + so; bl_base = y0l + so;
      } else {                               // L1 h-part = h1 pingpong slot t
        const size_t so = (size_t)(t & 1) * BHE + (size_t)(kq - 4) * 128;
        bh_base = h1h + so; bl_base = h1l + so;
      }
#pragma unroll
      for (int ct = 0; ct < 2; ++ct) {
        const size_t cb = (size_t)(ct * 16 + l15) * 512 + koff;
#pragma unroll
        for (int kk = 0; kk < 4; ++kk) {
          pbh[ct][kk] = ld128_sys(bh_base + cb + kk * 32);
          pbl[ct][kk] = ld128_sys(bl_base + cb + kk * 32);
        }
      }
      SCHED0();
      asm volatile("s_waitcnt vmcnt(0)" ::: "memory");
      SCHED0();
    }

    // phase D: acc += Wh*Bh + Wh*Bl + Wl*Bh  (96 MFMAs, 8 indep chains)
    f32x4 acc[4][2] = {};
#pragma unroll
    for (int kk = 0; kk < 4; ++kk) {
#pragma unroll
      for (int rt = 0; rt < 4; ++rt)
#pragma unroll
        for (int ct = 0; ct < 2; ++ct)
          acc[rt][ct] = __builtin_amdgcn_mfma_f32_16x16x32_bf16(wh[rt][kk], pbh[ct][kk], acc[rt][ct], 0, 0, 0);
#pragma unroll
      for (int rt = 0; rt < 4; ++rt)
#pragma unroll
        for (int ct = 0; ct < 2; ++ct)
          acc[rt][ct] = __builtin_amdgcn_mfma_f32_16x16x32_bf16(wh[rt][kk], pbl[ct][kk], acc[rt][ct], 0, 0, 0);
#pragma unroll
      for (int rt = 0; rt < 4; ++rt)
#pragma unroll
        for (int ct = 0; ct < 2; ++ct)
          acc[rt][ct] = __builtin_amdgcn_mfma_f32_16x16x32_bf16(wl[rt][kk], pbh[ct][kk], acc[rt][ct], 0, 0, 0);
    }

    // phase E: cross-wave K reduce via LDS
#pragma unroll
    for (int rt = 0; rt < 4; ++rt)
#pragma unroll
      for (int ct = 0; ct < 2; ++ct)
        red[wv][rt * 2 + ct][ln] = acc[rt][ct];
    __syncthreads();   // barrier 2

    // phase F: finalize — every wave owns one 16x16 tile
    {
      f32x4 s = red[0][wv][ln];
#pragma unroll
      for (int w = 1; w < 8; ++w) s += red[w][wv][ln];
      const float gi = s[0] + bias[0], gf = s[1] + bias[1];
      const float gg = s[2] + bias[2], go = s[3] + bias[3];
      const float iv = sigm(gi), fv = sigm(gf), gv = tanh_(gg), ov = sigm(go);
      creg = fv * creg + iv * gv;
      const float h = ov * tanh_(creg);
      const u16 hhi = f2bf(h), hlo = f2bf(h - bf2f(hhi));

      if (layer == 0) {
        const size_t base = (size_t)((t + 1) & (RING - 1)) * BHE + (size_t)bcol * HH + hidx;
        st16_sys(y0h + base, hhi); st16_sys(y0l + base, hlo);
      } else {
        const size_t base = (size_t)((t + 1) & 1) * BHE + (size_t)bcol * HH + hidx;
        st16_sys(h1h + base, hhi); st16_sys(h1l + base, hlo);
        out[(size_t)t * BHE + (size_t)bcol * HH + hidx] = h;   // y1 fp32, cached
      }
      if (t == TT - 1) {
        hnp[bcol * HH + hidx] = h;
        cnp[bcol * HH + hidx] = creg;
      }
    }
    __syncthreads();   // barrier 3: per-wave vmcnt(0) drain -> all stores at MALL

    // phase G: publish completed-step flag
    if (tid == 0)
      __hip_atomic_store(&ownS[wg], (u32)(t + 1), __ATOMIC_RELAXED, __HIP_MEMORY_SCOPE_AGENT);
  }
}

extern "C" void kernel_launch(void* const* d_in, const int* in_sizes, int n_in,
                              void* d_out, int out_size, void* d_ws, size_t ws_size,
                              hipStream_t stream) {
  (void)in_sizes; (void)n_in; (void)out_size; (void)ws_size;
  const float* x    = (const float*)d_in[0];
  const float* h0   = (const float*)d_in[1];
  const float* c0   = (const float*)d_in[2];
  const float* Wih0 = (const float*)d_in[3];
  const float* Whh0 = (const float*)d_in[4];
  const float* bih0 = (const float*)d_in[5];
  const float* bhh0 = (const float*)d_in[6];
  const float* Wih1 = (const float*)d_in[7];
  const float* Whh1 = (const float*)d_in[8];
  const float* bih1 = (const float*)d_in[9];
  const float* bhh1 = (const float*)d_in[10];
  float* out = (float*)d_out;

  char* w = (char*)d_ws;
  size_t off = 0;
  auto alloc = [&](size_t bytes) { void* q = w + off; off += (bytes + 255) & ~(size_t)255; return q; };
  u16* xh    = (u16*)alloc((size_t)TT * BB * II * 2);   // 64 MiB
  u16* xl    = (u16*)alloc((size_t)TT * BB * II * 2);   // 64 MiB
  u16* WH0   = (u16*)alloc((size_t)2048 * 1024 * 2);    // 4 MiB
  u16* WL0   = (u16*)alloc((size_t)2048 * 1024 * 2);
  u16* WH1   = (u16*)alloc((size_t)2048 * 1024 * 2);
  u16* WL1   = (u16*)alloc((size_t)2048 * 1024 * 2);
  float* bsum0 = (float*)alloc(2048 * 4);
  float* bsum1 = (float*)alloc(2048 * 4);
  u16* y0h   = (u16*)alloc((size_t)RING * BHE * 2);     // 512 KiB
  u16* y0l   = (u16*)alloc((size_t)RING * BHE * 2);
  u16* h1h   = (u16*)alloc((size_t)2 * BHE * 2);
  u16* h1l   = (u16*)alloc((size_t)2 * BHE * 2);
  u32* slots = (u32*)alloc(256);

  k_cvt_x<<<dim3(2048), dim3(256), 0, stream>>>(x, xh, xl);
  k_build_w<<<dim3(4096), dim3(256), 0, stream>>>(Wih0, Whh0, bih0, bhh0,
                                                  Wih1, Whh1, bih1, bhh1,
                                                  WH0, WL0, WH1, WL1, bsum0, bsum1);
  k_init<<<dim3(128), dim3(256), 0, stream>>>(h0, y0h, y0l, h1h, h1l, slots);
  k_scan<<<dim3(2 * NWGL), dim3(NT), 0, stream>>>(WH0, WL0, WH1, WL1, bsum0, bsum1,
                                                  xh, xl, y0h, y0l, h1h, h1l,
                                                  c0, out, slots);
}

// Round 8
// 8998.557 us; speedup vs baseline: 1.7814x; 1.7814x over previous
//
#include <hip/hip_runtime.h>
#include <stdint.h>

#define TT 2048
#define BB 32
#define II 512
#define HH 512
#define BHE (BB * HH)      // 16384
#define NT 512             // 8 waves per WG
#define RING 16            // y0 cross-layer ring slots
#define XCC_GETREG_IMM (20 | (31 << 11))   // hwreg(HW_REG_XCC_ID=20, off 0, size 32)

typedef unsigned short u16;
typedef unsigned int u32;
typedef __attribute__((ext_vector_type(8))) short bf16x8;
typedef __attribute__((ext_vector_type(4))) float f32x4;

__device__ __forceinline__ u16 f2bf(float f) {
  u32 u = __float_as_uint(f);
  return (u16)((u + 0x7fffu + ((u >> 16) & 1u)) >> 16);  // RNE
}
__device__ __forceinline__ float bf2f(u16 h) { return __uint_as_float(((u32)h) << 16); }
__device__ __forceinline__ float sigm(float x) { return 1.f / (1.f + __expf(-x)); }
__device__ __forceinline__ float tanh_(float x) {
  float xc = fminf(fmaxf(x, -15.f), 15.f);
  float e = __expf(-2.f * xc);
  return (1.f - e) / (1.f + e);
}

// Data-path scope primitives. L2 (same-XCD): sc0. SYS (cross-XCD via MALL): sc0 sc1 (R3/R5-proven).
// All asm loads are drained by the explicit s_waitcnt vmcnt(0) before use.
__device__ __forceinline__ bf16x8 ld128_l2(const u16* p) {
  bf16x8 r; asm volatile("global_load_dwordx4 %0, %1, off sc0" : "=v"(r) : "v"(p) : "memory"); return r;
}
__device__ __forceinline__ bf16x8 ld128_sys(const u16* p) {
  bf16x8 r; asm volatile("global_load_dwordx4 %0, %1, off sc0 sc1" : "=v"(r) : "v"(p) : "memory"); return r;
}
__device__ __forceinline__ void st16_l2(u16* p, u16 v) {
  u32 vv = v; asm volatile("global_store_short %0, %1, off sc0" :: "v"(p), "v"(vv) : "memory");
}
__device__ __forceinline__ void st16_sys(u16* p, u16 v) {
  u32 vv = v; asm volatile("global_store_short %0, %1, off sc0 sc1" :: "v"(p), "v"(vv) : "memory");
}

#define SCHED0() __builtin_amdgcn_sched_barrier(0)

// ---- prep: x fp32 -> 2-limb bf16 ----
__global__ void k_cvt_x(const float* __restrict__ x, u16* __restrict__ xh, u16* __restrict__ xl) {
  const long n = (long)TT * BB * II;
  long i = ((long)blockIdx.x * 256 + threadIdx.x) * 4;
  const long stride = (long)gridDim.x * 256 * 4;
  for (; i < n; i += stride) {
    float4 v = *(const float4*)(x + i);
    ushort4 h, l;
    h.x = f2bf(v.x); l.x = f2bf(v.x - bf2f(h.x));
    h.y = f2bf(v.y); l.y = f2bf(v.y - bf2f(h.y));
    h.z = f2bf(v.z); l.z = f2bf(v.z - bf2f(h.z));
    h.w = f2bf(v.w); l.w = f2bf(v.w - bf2f(h.w));
    *(ushort4*)(xh + i) = h;
    *(ushort4*)(xl + i) = l;
  }
}

// ---- prep: gate-permuted 2-limb weights. rr = hidx*4+q, srow = q*512+hidx ----
__global__ void k_build_w(const float* __restrict__ Wih0, const float* __restrict__ Whh0,
                          const float* __restrict__ bih0, const float* __restrict__ bhh0,
                          const float* __restrict__ Wih1, const float* __restrict__ Whh1,
                          const float* __restrict__ bih1, const float* __restrict__ bhh1,
                          u16* __restrict__ WH0, u16* __restrict__ WL0,
                          u16* __restrict__ WH1, u16* __restrict__ WL1,
                          float* __restrict__ bsum0, float* __restrict__ bsum1) {
  const int rr = blockIdx.x & 2047;
  const int layer = blockIdx.x >> 11;
  const float* Wih = layer ? Wih1 : Wih0;
  const float* Whh = layer ? Whh1 : Whh0;
  u16* WH = (layer ? WH1 : WH0) + ((size_t)rr << 10);
  u16* WL = (layer ? WL1 : WL0) + ((size_t)rr << 10);
  const int hidx = rr >> 2, q = rr & 3;
  const int srow = q * HH + hidx;
  const float* si = Wih + (size_t)srow * II;
  const float* sh = Whh + (size_t)srow * HH;
  for (int k = threadIdx.x; k < 512; k += 256) {
    float wi = si[k]; u16 a = f2bf(wi); WH[k] = a;       WL[k] = f2bf(wi - bf2f(a));
    float wh = sh[k]; u16 b = f2bf(wh); WH[512 + k] = b; WL[512 + k] = f2bf(wh - bf2f(b));
  }
  if (threadIdx.x == 0)
    (layer ? bsum1 : bsum0)[rr] = (layer ? bih1 : bih0)[srow] + (layer ? bhh1 : bhh0)[srow];
}

// ---- prep: h0 -> per-pod hloc slot0 (2-limb), zero control block ----
// hloc layout: [pid][slot2][bl16][hidx512], pid = layer*2 + batchhalf
__global__ void k_init(const float* __restrict__ h0,
                       u16* __restrict__ hlh, u16* __restrict__ hll,
                       u32* __restrict__ ctrl) {
  int i = blockIdx.x * 256 + threadIdx.x;
  if (i < 2 * BHE) {
    const int L = i >> 14, b = (i >> 9) & 31, hidx = i & 511;
    const int c = b >> 4, bl = b & 15, pid = L * 2 + c;
    float v = h0[i]; u16 hi = f2bf(v);
    hlh[pid * 16384 + bl * 512 + hidx] = hi;
    hll[pid * 16384 + bl * 512 + hidx] = f2bf(v - bf2f(hi));
  }
  if (i < 264) ctrl[i] = 0;   // flags[4][32] | ready | gmask | pad | podxcc[128]
}

// ---- persistent pod scan ----
// 4 pods = (layer x batch-half), 32 WGs each, grouped by blockIdx%8 (XCC-verified).
// Sync skeleton = R5 (proven): __hip_atomic flags/polls, __syncthreads barriers,
// flag = t+1 published after a full vmcnt(0) drain. sh_fast gates ONLY h-data scope.
__global__ __launch_bounds__(NT, 2) void k_scan(
    const u16* __restrict__ WH0, const u16* __restrict__ WL0,
    const u16* __restrict__ WH1, const u16* __restrict__ WL1,
    const float* __restrict__ bsum0, const float* __restrict__ bsum1,
    const u16* __restrict__ xh, const u16* __restrict__ xl,
    u16* __restrict__ y0xh, u16* __restrict__ y0xl,   // [2][RING][16][512]
    u16* __restrict__ hlh, u16* __restrict__ hll,     // [4][2][16][512]
    const float* __restrict__ c0, float* __restrict__ out,
    u32* __restrict__ ctrl) {
  const int g = blockIdx.x & 7;
  if (g >= 4) return;                      // groups 4-7 idle out
  const int r = blockIdx.x >> 3;           // role 0..31 within pod
  const int pid = g, layer = g >> 1, c = g & 1;

  __shared__ f32x4 red[8][4][64];          // 32 KiB
  __shared__ int sh_fast;

  const int tid = threadIdx.x, ln = tid & 63, wv = tid >> 6;
  const int l15 = ln & 15, l16 = ln >> 4, koff = l16 * 8;

  u32* flags  = ctrl;                      // [4][32]
  u32* intra  = flags + pid * 32;
  u32* othF   = flags + ((layer == 0) ? (2 + c) : c) * 32;  // L0: L1-pod flags (BP); L1: L0-pod flags
  u32* ready  = ctrl + 128;
  u32* gmask  = ctrl + 129;
  u32* podxcc = ctrl + 136;

  // ---- one-time: verify each pod's 32 WGs share an XCD (ran fine in R6/R7) ----
  if (tid == 0) {
    u32 xcc = __builtin_amdgcn_s_getreg(XCC_GETREG_IMM) & 0xffu;
    atomicOr(gmask, 1u << (xcc & 31u));
    __hip_atomic_store(&podxcc[pid * 32 + r], xcc | 0x100u, __ATOMIC_RELEASE, __HIP_MEMORY_SCOPE_AGENT);
    __hip_atomic_fetch_add(ready, 1u, __ATOMIC_ACQ_REL, __HIP_MEMORY_SCOPE_AGENT);
    while (__hip_atomic_load(ready, __ATOMIC_ACQUIRE, __HIP_MEMORY_SCOPE_AGENT) < 128u)
      __builtin_amdgcn_s_sleep(8);
    u32 v0 = __hip_atomic_load(&podxcc[pid * 32], __ATOMIC_ACQUIRE, __HIP_MEMORY_SCOPE_AGENT);
    int agree = 1;
    for (int j = 1; j < 32; ++j)
      agree &= (__hip_atomic_load(&podxcc[pid * 32 + j], __ATOMIC_ACQUIRE, __HIP_MEMORY_SCOPE_AGENT) == v0);
    u32 gm = __hip_atomic_load(gmask, __ATOMIC_ACQUIRE, __HIP_MEMORY_SCOPE_AGENT);
    sh_fast = (agree && __popc(gm) >= 2) ? 1 : 0;
  }
  __syncthreads();
  const bool fast = sh_fast != 0;

  // ---- pin this wave's weight fragments (2-limb, 4 row-tiles x 4 k-frags = 128 VGPR) ----
  const u16* WHp = layer ? WH1 : WH0;
  const u16* WLp = layer ? WL1 : WL0;
  bf16x8 wh[4][4], wl[4][4];
#pragma unroll
  for (int rt = 0; rt < 4; ++rt) {
    const size_t row = (size_t)(r * 64 + rt * 16 + l15) << 10;
#pragma unroll
    for (int kk = 0; kk < 4; ++kk) {
      const size_t kpos = (size_t)wv * 128 + kk * 32 + koff;
      wh[rt][kk] = *(const bf16x8*)(WHp + row + kpos);
      wl[rt][kk] = *(const bf16x8*)(WLp + row + kpos);
    }
  }
#pragma unroll
  for (int rt = 0; rt < 4; ++rt)
#pragma unroll
    for (int kk = 0; kk < 4; ++kk)
      asm volatile("" : "+v"(wh[rt][kk]), "+v"(wl[rt][kk]));

  // finalize identity (waves 0-3 own row-tile rt = wv)
  const int hidx = r * 16 + (wv & 3) * 4 + l16;
  const int bglob = c * 16 + l15;
  const float* bsum = layer ? bsum1 : bsum0;
  f32x4 bias = *(const f32x4*)(bsum + hidx * 4);
  float creg = c0[layer * BHE + bglob * HH + hidx];

  u16* myhlh = hlh + pid * 16384;   // [slot2][bl16][hidx512]
  u16* myhll = hll + pid * 16384;
  u16* y0h = y0xh + c * (RING * 8192);
  u16* y0l = y0xl + c * (RING * 8192);
  float* hnp = out + (size_t)TT * BHE + (size_t)layer * BHE;
  float* cnp = out + (size_t)TT * BHE + 2 * BHE + (size_t)layer * BHE;

  for (int t = 0; t < TT; ++t) {
    bf16x8 pbh[4], pbl[4];

    // ---- phase A: L0 x prefetch (cached, read-only, flag-independent) ----
    if (layer == 0 && wv < 4) {
      const u16* p1 = xh + (size_t)t * BHE + (size_t)bglob * 512 + wv * 128 + koff;
      const u16* p2 = xl + (size_t)t * BHE + (size_t)bglob * 512 + wv * 128 + koff;
#pragma unroll
      for (int kk = 0; kk < 4; ++kk) {
        pbh[kk] = *(const bf16x8*)(p1 + kk * 32);
        pbl[kk] = *(const bf16x8*)(p2 + kk * 32);
      }
    }

    // ---- phase B: wave 0 polls (R5 machinery). lanes 0-31: intra >= t.
    //      lanes 32-63: L1 needs L0 flags >= t+1; L0 (t>=16) needs L1 flags >= t-15. ----
    if (wv == 0) {
      const u32 tgtOwn = (u32)t;
      const int needO = (layer == 1) || (t >= 16);
      const u32 tgtO = (layer == 1) ? (u32)(t + 1) : (u32)(t - 15);
      for (;;) {
        int ok = 1;
        if (ln < 32) ok = (__hip_atomic_load(&intra[ln], __ATOMIC_RELAXED, __HIP_MEMORY_SCOPE_AGENT) >= tgtOwn);
        else if (needO) ok = (__hip_atomic_load(&othF[ln - 32], __ATOMIC_RELAXED, __HIP_MEMORY_SCOPE_AGENT) >= tgtO);
        if (__all(ok)) break;
        __builtin_amdgcn_s_sleep(1);
      }
    }
    __syncthreads();   // barrier 1: flags satisfied -> state readable

    // ---- phase C: remaining B loads ----
    if (layer == 0) {
      if (wv >= 4) {   // L0 h-part: pod-local (L2 scope in fast mode)
        const size_t base = ((size_t)(t & 1) * 16 + l15) * 512 + (wv - 4) * 128 + koff;
#pragma unroll
        for (int kk = 0; kk < 4; ++kk) {
          const u16* ph = myhlh + base + kk * 32;
          const u16* pl = myhll + base + kk * 32;
          pbh[kk] = fast ? ld128_l2(ph) : ld128_sys(ph);
          pbl[kk] = fast ? ld128_l2(pl) : ld128_sys(pl);
        }
      }
    } else {
      if (wv < 4) {    // L1 x-part: y0x ring slot t+1 (cross-XCD, sys)
        const size_t base = ((size_t)((t + 1) & (RING - 1)) * 16 + l15) * 512 + wv * 128 + koff;
#pragma unroll
        for (int kk = 0; kk < 4; ++kk) {
          pbh[kk] = ld128_sys(y0h + base + kk * 32);
          pbl[kk] = ld128_sys(y0l + base + kk * 32);
        }
      } else {         // L1 h-part: pod-local
        const size_t base = ((size_t)(t & 1) * 16 + l15) * 512 + (wv - 4) * 128 + koff;
#pragma unroll
        for (int kk = 0; kk < 4; ++kk) {
          const u16* ph = myhlh + base + kk * 32;
          const u16* pl = myhll + base + kk * 32;
          pbh[kk] = fast ? ld128_l2(ph) : ld128_sys(ph);
          pbl[kk] = fast ? ld128_l2(pl) : ld128_sys(pl);
        }
      }
    }
    SCHED0();
    asm volatile("s_waitcnt vmcnt(0)" ::: "memory");   // all B fragments resident
    SCHED0();

    // ---- phase D: acc += Wh*Bh + Wh*Bl + Wl*Bh (48 MFMA, 4 indep chains) ----
    f32x4 a0 = {0.f, 0.f, 0.f, 0.f}, a1 = a0, a2 = a0, a3 = a0;
#pragma unroll
    for (int kk = 0; kk < 4; ++kk) {
      a0 = __builtin_amdgcn_mfma_f32_16x16x32_bf16(wh[0][kk], pbh[kk], a0, 0, 0, 0);
      a1 = __builtin_amdgcn_mfma_f32_16x16x32_bf16(wh[1][kk], pbh[kk], a1, 0, 0, 0);
      a2 = __builtin_amdgcn_mfma_f32_16x16x32_bf16(wh[2][kk], pbh[kk], a2, 0, 0, 0);
      a3 = __builtin_amdgcn_mfma_f32_16x16x32_bf16(wh[3][kk], pbh[kk], a3, 0, 0, 0);
      a0 = __builtin_amdgcn_mfma_f32_16x16x32_bf16(wh[0][kk], pbl[kk], a0, 0, 0, 0);
      a1 = __builtin_amdgcn_mfma_f32_16x16x32_bf16(wh[1][kk], pbl[kk], a1, 0, 0, 0);
      a2 = __builtin_amdgcn_mfma_f32_16x16x32_bf16(wh[2][kk], pbl[kk], a2, 0, 0, 0);
      a3 = __builtin_amdgcn_mfma_f32_16x16x32_bf16(wh[3][kk], pbl[kk], a3, 0, 0, 0);
      a0 = __builtin_amdgcn_mfma_f32_16x16x32_bf16(wl[0][kk], pbh[kk], a0, 0, 0, 0);
      a1 = __builtin_amdgcn_mfma_f32_16x16x32_bf16(wl[1][kk], pbh[kk], a1, 0, 0, 0);
      a2 = __builtin_amdgcn_mfma_f32_16x16x32_bf16(wl[2][kk], pbh[kk], a2, 0, 0, 0);
      a3 = __builtin_amdgcn_mfma_f32_16x16x32_bf16(wl[3][kk], pbh[kk], a3, 0, 0, 0);
    }

    // ---- phase E: cross-wave K reduce (plain LDS; __syncthreads handles lgkm) ----
    red[wv][0][ln] = a0; red[wv][1][ln] = a1; red[wv][2][ln] = a2; red[wv][3][ln] = a3;
    __syncthreads();   // barrier 2

    // ---- phase F: finalize (waves 0-3, row-tile = wv) ----
    if (wv < 4) {
      f32x4 s = red[0][wv][ln];
#pragma unroll
      for (int w2 = 1; w2 < 8; ++w2) s += red[w2][wv][ln];
      const float gi = s[0] + bias[0], gf = s[1] + bias[1];
      const float gg = s[2] + bias[2], go = s[3] + bias[3];
      const float iv = sigm(gi), fv = sigm(gf), gv = tanh_(gg), ov = sigm(go);
      creg = fv * creg + iv * gv;
      const float h = ov * tanh_(creg);
      const u16 hhi = f2bf(h), hlo = f2bf(h - bf2f(hhi));

      // pod-local h (pod-RELATIVE offset)
      const size_t lb = ((size_t)((t + 1) & 1) * 16 + l15) * 512 + hidx;
      if (fast) { st16_l2(myhlh + lb, hhi); st16_l2(myhll + lb, hlo); }
      else      { st16_sys(myhlh + lb, hhi); st16_sys(myhll + lb, hlo); }
      // cross-pod / output
      if (layer == 0) {
        const size_t xb = ((size_t)((t + 1) & (RING - 1)) * 16 + l15) * 512 + hidx;
        st16_sys(y0h + xb, hhi); st16_sys(y0l + xb, hlo);
      } else {
        out[(size_t)t * BHE + (size_t)bglob * 512 + hidx] = h;   // y1 fp32, cached
      }
      if (t == TT - 1) {
        hnp[bglob * 512 + hidx] = h;
        cnp[bglob * 512 + hidx] = creg;
      }
    }
    asm volatile("s_waitcnt vmcnt(0)" ::: "memory");   // every wave drains ALL its stores
    __syncthreads();                                    // barrier 3: whole WG drained

    // ---- phase G: publish flag = t+1 (R5 machinery) ----
    if (tid == 0)
      __hip_atomic_store(&intra[r], (u32)(t + 1), __ATOMIC_RELAXED, __HIP_MEMORY_SCOPE_AGENT);
  }
}

extern "C" void kernel_launch(void* const* d_in, const int* in_sizes, int n_in,
                              void* d_out, int out_size, void* d_ws, size_t ws_size,
                              hipStream_t stream) {
  (void)in_sizes; (void)n_in; (void)out_size; (void)ws_size;
  const float* x    = (const float*)d_in[0];
  const float* h0   = (const float*)d_in[1];
  const float* c0   = (const float*)d_in[2];
  const float* Wih0 = (const float*)d_in[3];
  const float* Whh0 = (const float*)d_in[4];
  const float* bih0 = (const float*)d_in[5];
  const float* bhh0 = (const float*)d_in[6];
  const float* Wih1 = (const float*)d_in[7];
  const float* Whh1 = (const float*)d_in[8];
  const float* bih1 = (const float*)d_in[9];
  const float* bhh1 = (const float*)d_in[10];
  float* out = (float*)d_out;

  char* w = (char*)d_ws;
  size_t off = 0;
  auto alloc = [&](size_t bytes) { void* q = w + off; off += (bytes + 255) & ~(size_t)255; return q; };
  u16* xh    = (u16*)alloc((size_t)TT * BB * II * 2);   // 64 MiB
  u16* xl    = (u16*)alloc((size_t)TT * BB * II * 2);   // 64 MiB
  u16* WH0   = (u16*)alloc((size_t)2048 * 1024 * 2);    // 4 MiB
  u16* WL0   = (u16*)alloc((size_t)2048 * 1024 * 2);
  u16* WH1   = (u16*)alloc((size_t)2048 * 1024 * 2);
  u16* WL1   = (u16*)alloc((size_t)2048 * 1024 * 2);
  float* bsum0 = (float*)alloc(2048 * 4);
  float* bsum1 = (float*)alloc(2048 * 4);
  u16* y0xh  = (u16*)alloc((size_t)2 * RING * 8192 * 2);  // [2][16][16][512]
  u16* y0xl  = (u16*)alloc((size_t)2 * RING * 8192 * 2);
  u16* hlh   = (u16*)alloc((size_t)4 * 16384 * 2);        // [4][2][16][512]
  u16* hll   = (u16*)alloc((size_t)4 * 16384 * 2);
  u32* ctrl  = (u32*)alloc(2048);

  k_cvt_x<<<dim3(2048), dim3(256), 0, stream>>>(x, xh, xl);
  k_build_w<<<dim3(4096), dim3(256), 0, stream>>>(Wih0, Whh0, bih0, bhh0,
                                                  Wih1, Whh1, bih1, bhh1,
                                                  WH0, WL0, WH1, WL1, bsum0, bsum1);
  k_init<<<dim3(128), dim3(256), 0, stream>>>(h0, hlh, hll, ctrl);
  k_scan<<<dim3(256), dim3(NT), 0, stream>>>(WH0, WL0, WH1, WL1, bsum0, bsum1,
                                             xh, xl, y0xh, y0xl, hlh, hll,
                                             c0, out, ctrl);
}